// Round 1
// baseline (920.960 us; speedup 1.0000x reference)
//
#include <hip/hip_runtime.h>
#include <stdint.h>

// Problem constants
constexpr int HD    = 1024;   // hidden
constexpr int BB    = 64;     // batch
constexpr int TT    = 512;    // time
constexpr int MR    = BB * TT;   // 32768 rows
constexpr int KA    = 49;     // attention slots

using bf16x8 = __attribute__((ext_vector_type(8))) short;
using f32x4  = __attribute__((ext_vector_type(4))) float;

__device__ __forceinline__ unsigned f2bf1(float f) {
    unsigned u = __builtin_bit_cast(unsigned, f);
    return (u + 0x7FFFu + ((u >> 16) & 1u)) >> 16;   // RNE fp32 -> bf16 (as uint)
}
__device__ __forceinline__ unsigned pack2(float lo, float hi) {
    return (f2bf1(lo) & 0xFFFFu) | (f2bf1(hi) << 16);
}
__device__ __forceinline__ float bf2f(unsigned short s) {
    unsigned u = ((unsigned)s) << 16;
    return __builtin_bit_cast(float, u);
}
__device__ __forceinline__ float fast_rcp(float x) { return __builtin_amdgcn_rcpf(x); }
__device__ __forceinline__ float fast_tanh(float x) {
    float ax = fabsf(x);
    float e  = __expf(-2.0f * ax);
    float t  = (1.0f - e) * fast_rcp(1.0f + e);
    return copysignf(t, x);
}
__device__ __forceinline__ float fast_sigmoid(float x) {
    return fast_rcp(1.0f + __expf(-x));
}

// ---------------------------------------------------------------------------
// P2: cv[b,k,j] = sum_h V[b,k,h] * Wv[j,h]    grid (64, 7), block 256
// ---------------------------------------------------------------------------
__global__ void cv_kernel(const float* __restrict__ V, const float* __restrict__ Wv,
                          float* __restrict__ cv) {
    __shared__ float wv[7][HD];
    __shared__ float vrow[HD];
    const int b = blockIdx.x, jg = blockIdx.y;
    const int tid = threadIdx.x;
    for (int idx = tid; idx < 7 * HD; idx += 256) {
        int jj = idx >> 10;
        wv[jj][idx & (HD - 1)] = Wv[(size_t)(jg * 7 + jj) * HD + (idx & (HD - 1))];
    }
    const int w = tid >> 6, lane = tid & 63;
    for (int k = 0; k < KA; ++k) {
        __syncthreads();
        ((float4*)vrow)[tid] = ((const float4*)(V + (size_t)(b * KA + k) * HD))[tid];
        __syncthreads();
        for (int jj = w; jj < 7; jj += 4) {
            float s = 0.f;
            #pragma unroll
            for (int i = 0; i < 16; ++i)
                s += vrow[lane + 64 * i] * wv[jj][lane + 64 * i];
            #pragma unroll
            for (int off = 32; off; off >>= 1) s += __shfl_xor(s, off);
            if (lane == 0) cv[((size_t)b * KA + k) * KA + jg * 7 + jj] = s;
        }
    }
}

// ---------------------------------------------------------------------------
// P1: Vt[b][h][k(0..63)] = bf16(V[b][k][h]), k>=49 -> 0.  grid (64,16), block 256
// ---------------------------------------------------------------------------
__global__ void vt_kernel(const float* __restrict__ V, unsigned short* __restrict__ Vt) {
    __shared__ float tile[KA][65];
    const int b = blockIdx.x, hg = blockIdx.y;
    const int tid = threadIdx.x;
    for (int idx = tid; idx < KA * 64; idx += 256) {
        int k = idx >> 6, c = idx & 63;
        tile[k][c] = V[(size_t)(b * KA + k) * HD + hg * 64 + c];
    }
    __syncthreads();
    const int c = tid & 63, kq = tid >> 6;   // kq in 0..3
    unsigned short tmp[16];
    #pragma unroll
    for (int u = 0; u < 16; ++u) {
        int k = kq * 16 + u;
        float f = (k < KA) ? tile[k][c] : 0.f;
        tmp[u] = (unsigned short)f2bf1(f);
    }
    unsigned short* dst = Vt + ((size_t)b * HD + hg * 64 + c) * 64 + kq * 16;
    ((uint4*)dst)[0] = *((const uint4*)tmp);
    ((uint4*)dst)[1] = *((const uint4*)(tmp + 8));
}

// ---------------------------------------------------------------------------
// P3: s_t = sigmoid(x @ Wx^T) * tanh(cells), stored bf16.
// MFMA bf16 16x16x32, 128x128 tile, BK=64, XOR-swizzled LDS chunks.
// grid (8, 256), block 256
// ---------------------------------------------------------------------------
__launch_bounds__(256, 2)
__global__ void gate_gemm(const float* __restrict__ x, const float* __restrict__ Wx,
                          const float* __restrict__ cells, unsigned short* __restrict__ s_t) {
    __shared__ uint4 As[128 * 8];
    __shared__ uint4 Bs[128 * 8];
    const int tid = threadIdx.x;
    const int w = tid >> 6, lane = tid & 63, quad = lane >> 4, l15 = lane & 15;
    const int n0 = blockIdx.x * 128, m0 = blockIdx.y * 128;
    const int wm = (w >> 1) * 64, wn = (w & 1) * 64;
    f32x4 acc[4][4] = {};
    for (int kt = 0; kt < HD; kt += 64) {
        __syncthreads();
        #pragma unroll
        for (int it = 0; it < 4; ++it) {
            int c = it * 256 + tid;
            int row = c >> 3, c8 = c & 7;
            const float* gp = x + (size_t)(m0 + row) * HD + kt + c8 * 8;
            float4 f0 = ((const float4*)gp)[0];
            float4 f1 = ((const float4*)gp)[1];
            uint4 v; v.x = pack2(f0.x, f0.y); v.y = pack2(f0.z, f0.w);
            v.z = pack2(f1.x, f1.y); v.w = pack2(f1.z, f1.w);
            As[row * 8 + (c8 ^ (row & 7))] = v;
        }
        #pragma unroll
        for (int it = 0; it < 4; ++it) {
            int c = it * 256 + tid;
            int row = c >> 3, c8 = c & 7;
            const float* gp = Wx + (size_t)(n0 + row) * HD + kt + c8 * 8;
            float4 f0 = ((const float4*)gp)[0];
            float4 f1 = ((const float4*)gp)[1];
            uint4 v; v.x = pack2(f0.x, f0.y); v.y = pack2(f0.z, f0.w);
            v.z = pack2(f1.x, f1.y); v.w = pack2(f1.z, f1.w);
            Bs[row * 8 + (c8 ^ (row & 7))] = v;
        }
        __syncthreads();
        #pragma unroll
        for (int kc = 0; kc < 2; ++kc) {
            bf16x8 af[4], bfr[4];
            #pragma unroll
            for (int i = 0; i < 4; ++i) {
                int r = wm + i * 16 + l15;
                af[i] = *((const bf16x8*)&As[r * 8 + ((kc * 4 + quad) ^ (r & 7))]);
            }
            #pragma unroll
            for (int j = 0; j < 4; ++j) {
                int r = wn + j * 16 + l15;
                bfr[j] = *((const bf16x8*)&Bs[r * 8 + ((kc * 4 + quad) ^ (r & 7))]);
            }
            #pragma unroll
            for (int i = 0; i < 4; ++i)
                #pragma unroll
                for (int j = 0; j < 4; ++j)
                    acc[i][j] = __builtin_amdgcn_mfma_f32_16x16x32_bf16(af[i], bfr[j], acc[i][j], 0, 0, 0);
        }
    }
    #pragma unroll
    for (int i = 0; i < 4; ++i) {
        #pragma unroll
        for (int reg = 0; reg < 4; ++reg) {
            int rowg = m0 + wm + i * 16 + quad * 4 + reg;
            const float* crow = cells + (size_t)rowg * HD;
            unsigned short* srow = s_t + (size_t)rowg * HD;
            #pragma unroll
            for (int j = 0; j < 4; ++j) {
                int colg = n0 + wn + j * 16 + l15;
                float z = acc[i][j][reg];
                float sv = fast_sigmoid(z) * fast_tanh(crow[colg]);
                srow[colg] = (unsigned short)f2bf1(sv);
            }
        }
    }
}

// ---------------------------------------------------------------------------
// P4: out[m][0..63] = A[m,:] @ Bw[j,:]^T  (j>=49 zero-padded).
// M-tile 128, N=64, BK=64. A is fp32 or bf16 (template). grid (256), block 256
// ---------------------------------------------------------------------------
template <bool A_BF16>
__launch_bounds__(256, 2)
__global__ void small_gemm(const void* __restrict__ Av, const float* __restrict__ Bw,
                           float* __restrict__ outp) {
    __shared__ uint4 As[128 * 8];
    __shared__ uint4 Bs[64 * 8];
    const int tid = threadIdx.x;
    const int w = tid >> 6, lane = tid & 63, quad = lane >> 4, l15 = lane & 15;
    const int m0 = blockIdx.x * 128;
    const int wm = w * 32;
    f32x4 acc[2][4] = {};
    for (int kt = 0; kt < HD; kt += 64) {
        __syncthreads();
        #pragma unroll
        for (int it = 0; it < 4; ++it) {
            int c = it * 256 + tid;
            int row = c >> 3, c8 = c & 7;
            uint4 v;
            if (A_BF16) {
                const unsigned short* gp = ((const unsigned short*)Av) + (size_t)(m0 + row) * HD + kt + c8 * 8;
                v = ((const uint4*)gp)[0];
            } else {
                const float* gp = ((const float*)Av) + (size_t)(m0 + row) * HD + kt + c8 * 8;
                float4 f0 = ((const float4*)gp)[0];
                float4 f1 = ((const float4*)gp)[1];
                v.x = pack2(f0.x, f0.y); v.y = pack2(f0.z, f0.w);
                v.z = pack2(f1.x, f1.y); v.w = pack2(f1.z, f1.w);
            }
            As[row * 8 + (c8 ^ (row & 7))] = v;
        }
        #pragma unroll
        for (int it = 0; it < 2; ++it) {
            int c = it * 256 + tid;
            int row = c >> 3, c8 = c & 7;   // row 0..63
            uint4 v; v.x = v.y = v.z = v.w = 0u;
            if (row < KA) {
                const float* gp = Bw + (size_t)row * HD + kt + c8 * 8;
                float4 f0 = ((const float4*)gp)[0];
                float4 f1 = ((const float4*)gp)[1];
                v.x = pack2(f0.x, f0.y); v.y = pack2(f0.z, f0.w);
                v.z = pack2(f1.x, f1.y); v.w = pack2(f1.z, f1.w);
            }
            Bs[row * 8 + (c8 ^ (row & 7))] = v;
        }
        __syncthreads();
        #pragma unroll
        for (int kc = 0; kc < 2; ++kc) {
            bf16x8 af[2], bfr[4];
            #pragma unroll
            for (int i = 0; i < 2; ++i) {
                int r = wm + i * 16 + l15;
                af[i] = *((const bf16x8*)&As[r * 8 + ((kc * 4 + quad) ^ (r & 7))]);
            }
            #pragma unroll
            for (int j = 0; j < 4; ++j) {
                int r = j * 16 + l15;
                bfr[j] = *((const bf16x8*)&Bs[r * 8 + ((kc * 4 + quad) ^ (r & 7))]);
            }
            #pragma unroll
            for (int i = 0; i < 2; ++i)
                #pragma unroll
                for (int j = 0; j < 4; ++j)
                    acc[i][j] = __builtin_amdgcn_mfma_f32_16x16x32_bf16(af[i], bfr[j], acc[i][j], 0, 0, 0);
        }
    }
    #pragma unroll
    for (int i = 0; i < 2; ++i)
        #pragma unroll
        for (int reg = 0; reg < 4; ++reg) {
            int rowg = m0 + wm + i * 16 + quad * 4 + reg;
            #pragma unroll
            for (int j = 0; j < 4; ++j)
                outp[(size_t)rowg * 64 + j * 16 + l15] = acc[i][j][reg];
        }
}

// ---------------------------------------------------------------------------
// P5: attention scores. grid (64, 8), block 256; each wave does 16 t's.
// lane = k; in-lane j loop; alpha bf16 [MR][64], beta fp32 [MR].
// ---------------------------------------------------------------------------
__global__ void attn_kernel(const float* __restrict__ g, const float* __restrict__ ss,
                            const float* __restrict__ cv, const float* __restrict__ Wh,
                            unsigned short* __restrict__ alpha, float* __restrict__ beta) {
    __shared__ float cvs[KA * KA];
    const int b = blockIdx.x, t0 = blockIdx.y * 64;
    const int tid = threadIdx.x, w = tid >> 6, lane = tid & 63;
    for (int idx = tid; idx < KA * KA; idx += 256)
        cvs[idx] = cv[(size_t)b * KA * KA + idx];
    const float wh_l = (lane < KA) ? Wh[lane] : 0.f;
    __syncthreads();
    for (int ti = 0; ti < 16; ++ti) {
        const int t = t0 + ti * 4 + w;
        const size_t row = (size_t)b * TT + t;
        const float gj  = g[row * 64 + lane];            // cols >=49 are 0
        const float ssj = ss[row * 64 + lane] + gj;
        float ve = fast_tanh(ssj) * wh_l;
        #pragma unroll
        for (int off = 32; off; off >>= 1) ve += __shfl_xor(ve, off);
        // ve == z_ext (all lanes)
        float zk = 0.f;
        const float* cr = cvs + lane * KA;               // lane = k
        for (int j = 0; j < KA; ++j) {
            float gb = __shfl(gj, j);
            float wb = __shfl(wh_l, j);
            zk += fast_tanh(cr[j] + gb) * wb;
        }
        float zval = (lane < KA) ? zk : -1e30f;
        float M = zval;
        #pragma unroll
        for (int off = 32; off; off >>= 1) M = fmaxf(M, __shfl_xor(M, off));
        M = fmaxf(M, ve);
        float ek = (lane < KA) ? __expf(zk - M) : 0.f;
        float S = ek;
        #pragma unroll
        for (int off = 32; off; off >>= 1) S += __shfl_xor(S, off);
        float eext = __expf(ve - M);
        float bet  = eext * fast_rcp(S + eext);
        float al   = ek * fast_rcp(S);
        alpha[row * 64 + lane] = (unsigned short)f2bf1(al);
        if (lane == 0) beta[row] = bet;
    }
}

// ---------------------------------------------------------------------------
// P6: c_t = alpha @ V[b]  (MFMA, K=64 single step), fused final output:
// out = beta*s_t + (1-beta)*c_t + hiddens.  grid (8, 256), block 256
// ---------------------------------------------------------------------------
__launch_bounds__(256, 2)
__global__ void ct_final(const unsigned short* __restrict__ alpha, const unsigned short* __restrict__ Vt,
                         const unsigned short* __restrict__ s_t, const float* __restrict__ hiddens,
                         const float* __restrict__ beta, float* __restrict__ out) {
    __shared__ uint4 As[128 * 8];
    __shared__ uint4 Bs[128 * 8];
    const int tid = threadIdx.x;
    const int w = tid >> 6, lane = tid & 63, quad = lane >> 4, l15 = lane & 15;
    const int n0 = blockIdx.x * 128, m0 = blockIdx.y * 128;
    const int b = m0 >> 9;                  // 512 rows per batch; 128 | 512
    const int wm = (w >> 1) * 64, wn = (w & 1) * 64;
    f32x4 acc[4][4] = {};
    #pragma unroll
    for (int it = 0; it < 4; ++it) {
        int c = it * 256 + tid;
        int row = c >> 3, c8 = c & 7;
        As[row * 8 + (c8 ^ (row & 7))] = ((const uint4*)(alpha + (size_t)(m0 + row) * 64))[c8];
    }
    #pragma unroll
    for (int it = 0; it < 4; ++it) {
        int c = it * 256 + tid;
        int row = c >> 3, c8 = c & 7;
        Bs[row * 8 + (c8 ^ (row & 7))] = ((const uint4*)(Vt + ((size_t)b * HD + n0 + row) * 64))[c8];
    }
    __syncthreads();
    #pragma unroll
    for (int kc = 0; kc < 2; ++kc) {
        bf16x8 af[4], bfr[4];
        #pragma unroll
        for (int i = 0; i < 4; ++i) {
            int r = wm + i * 16 + l15;
            af[i] = *((const bf16x8*)&As[r * 8 + ((kc * 4 + quad) ^ (r & 7))]);
        }
        #pragma unroll
        for (int j = 0; j < 4; ++j) {
            int r = wn + j * 16 + l15;
            bfr[j] = *((const bf16x8*)&Bs[r * 8 + ((kc * 4 + quad) ^ (r & 7))]);
        }
        #pragma unroll
        for (int i = 0; i < 4; ++i)
            #pragma unroll
            for (int j = 0; j < 4; ++j)
                acc[i][j] = __builtin_amdgcn_mfma_f32_16x16x32_bf16(af[i], bfr[j], acc[i][j], 0, 0, 0);
    }
    #pragma unroll
    for (int i = 0; i < 4; ++i) {
        #pragma unroll
        for (int reg = 0; reg < 4; ++reg) {
            int rowg = m0 + wm + i * 16 + quad * 4 + reg;
            float bet = beta[rowg];
            const unsigned short* sr = s_t + (size_t)rowg * HD;
            const float* hr = hiddens + (size_t)rowg * HD;
            float* orow = out + (size_t)rowg * HD;
            #pragma unroll
            for (int j = 0; j < 4; ++j) {
                int colg = n0 + wn + j * 16 + l15;
                float ct = acc[i][j][reg];
                float sv = bf2f(sr[colg]);
                orow[colg] = bet * sv + (1.f - bet) * ct + hr[colg];
            }
        }
    }
}

// ---------------------------------------------------------------------------
extern "C" void kernel_launch(void* const* d_in, const int* in_sizes, int n_in,
                              void* d_out, int out_size, void* d_ws, size_t ws_size,
                              hipStream_t stream) {
    (void)in_sizes; (void)n_in; (void)out_size; (void)ws_size;
    const float* x       = (const float*)d_in[0];
    const float* hiddens = (const float*)d_in[1];
    const float* cells   = (const float*)d_in[2];
    const float* V       = (const float*)d_in[3];
    const float* Wx      = (const float*)d_in[4];
    // d_in[5] = Whh — multiplied by h_prev==0 in the reference; unused.
    const float* Wv      = (const float*)d_in[6];
    const float* Wg      = (const float*)d_in[7];
    const float* Ws      = (const float*)d_in[8];
    const float* Wh      = (const float*)d_in[9];
    float* out = (float*)d_out;

    char* ws = (char*)d_ws;
    unsigned short* s_t   = (unsigned short*)ws;  ws += (size_t)MR * HD * 2;        // 64 MiB
    unsigned short* alpha = (unsigned short*)ws;  ws += (size_t)MR * 64 * 2;        // 4 MiB
    unsigned short* Vt    = (unsigned short*)ws;  ws += (size_t)BB * HD * 64 * 2;   // 8 MiB
    float* gbuf = (float*)ws;                     ws += (size_t)MR * 64 * 4;        // 8 MiB
    float* ssb  = (float*)ws;                     ws += (size_t)MR * 64 * 4;        // 8 MiB
    float* cvb  = (float*)ws;                     ws += (size_t)BB * KA * KA * 4;   // 0.6 MiB
    float* beta = (float*)ws;                     ws += (size_t)MR * 4;             // 128 KiB

    cv_kernel<<<dim3(BB, 7),  dim3(256), 0, stream>>>(V, Wv, cvb);
    vt_kernel<<<dim3(BB, 16), dim3(256), 0, stream>>>(V, Vt);
    small_gemm<false><<<dim3(MR / 128), dim3(256), 0, stream>>>((const void*)hiddens, Wg, gbuf);
    gate_gemm<<<dim3(8, MR / 128), dim3(256), 0, stream>>>(x, Wx, cells, s_t);
    small_gemm<true><<<dim3(MR / 128), dim3(256), 0, stream>>>((const void*)s_t, Ws, ssb);
    attn_kernel<<<dim3(BB, 8), dim3(256), 0, stream>>>(gbuf, ssb, cvb, Wh, alpha, beta);
    ct_final<<<dim3(8, MR / 128), dim3(256), 0, stream>>>(alpha, Vt, s_t, hiddens, beta, out);
}

// Round 2
// 779.446 us; speedup vs baseline: 1.1816x; 1.1816x over previous
//
#include <hip/hip_runtime.h>
#include <stdint.h>

constexpr int HD = 1024;
constexpr int BB = 64;
constexpr int TT = 512;
constexpr int MR = BB * TT;   // 32768
constexpr int KA = 49;

using bf16x8 = __attribute__((ext_vector_type(8))) short;
using f32x4  = __attribute__((ext_vector_type(4))) float;
typedef unsigned short ushortt;

__device__ __forceinline__ unsigned f2bf1(float f) {
    unsigned u = __builtin_bit_cast(unsigned, f);
    return (u + 0x7FFFu + ((u >> 16) & 1u)) >> 16;   // RNE fp32 -> bf16
}
__device__ __forceinline__ unsigned pack2(float lo, float hi) {
    return (f2bf1(lo) & 0xFFFFu) | (f2bf1(hi) << 16);
}
__device__ __forceinline__ float bf2f(unsigned short s) {
    unsigned u = ((unsigned)s) << 16;
    return __builtin_bit_cast(float, u);
}
__device__ __forceinline__ float fast_rcp(float x) { return __builtin_amdgcn_rcpf(x); }
__device__ __forceinline__ float fast_tanh(float x) {
    float ax = fabsf(x);
    float e  = __expf(-2.0f * ax);
    float t  = (1.0f - e) * fast_rcp(1.0f + e);
    return copysignf(t, x);
}
__device__ __forceinline__ float fast_sigmoid(float x) {
    return fast_rcp(1.0f + __expf(-x));
}
// async 16B/lane global -> LDS (LDS dst is wave-uniform base + lane*16)
__device__ __forceinline__ void async_copy16(const void* gptr, void* ldsptr) {
    __builtin_amdgcn_global_load_lds(
        (const __attribute__((address_space(1))) unsigned int*)gptr,
        (__attribute__((address_space(3))) unsigned int*)ldsptr,
        16, 0, 0);
}

// ---------------------------------------------------------------------------
// fp32 -> bf16 elementwise, 8 elems/thread.  grid = n/8/256
// ---------------------------------------------------------------------------
__global__ void f32_to_bf16(const float* __restrict__ in, ushortt* __restrict__ outp) {
    int i = blockIdx.x * 256 + threadIdx.x;
    const float4* p = (const float4*)in + (size_t)i * 2;
    float4 f0 = p[0], f1 = p[1];
    uint4 v; v.x = pack2(f0.x, f0.y); v.y = pack2(f0.z, f0.w);
    v.z = pack2(f1.x, f1.y); v.w = pack2(f1.z, f1.w);
    ((uint4*)outp)[i] = v;
}

// W[49][1024] fp32 -> out[64][1024] bf16, rows>=49 zero.  grid 32, block 256
__global__ void cvt_w49(const float* __restrict__ W, ushortt* __restrict__ outp) {
    int i = blockIdx.x * 256 + threadIdx.x;   // 8192 threads
    int row = i >> 7, c8 = i & 127;
    uint4 v; v.x = v.y = v.z = v.w = 0u;
    if (row < KA) {
        const float4* p = (const float4*)(W + (size_t)row * HD) + c8 * 2;
        float4 f0 = p[0], f1 = p[1];
        v.x = pack2(f0.x, f0.y); v.y = pack2(f0.z, f0.w);
        v.z = pack2(f1.x, f1.y); v.w = pack2(f1.z, f1.w);
    }
    ((uint4*)outp)[i] = v;
}

// ---------------------------------------------------------------------------
// cv[b,k,j] = sum_h V[b,k,h] * Wv[j,h]    grid (64, 7), block 256
// ---------------------------------------------------------------------------
__global__ void cv_kernel(const float* __restrict__ V, const float* __restrict__ Wv,
                          float* __restrict__ cv) {
    __shared__ float wv[7][HD];
    __shared__ float vrow[HD];
    const int b = blockIdx.x, jg = blockIdx.y;
    const int tid = threadIdx.x;
    for (int idx = tid; idx < 7 * HD; idx += 256) {
        int jj = idx >> 10;
        wv[jj][idx & (HD - 1)] = Wv[(size_t)(jg * 7 + jj) * HD + (idx & (HD - 1))];
    }
    const int w = tid >> 6, lane = tid & 63;
    for (int k = 0; k < KA; ++k) {
        __syncthreads();
        ((float4*)vrow)[tid] = ((const float4*)(V + (size_t)(b * KA + k) * HD))[tid];
        __syncthreads();
        for (int jj = w; jj < 7; jj += 4) {
            float s = 0.f;
            #pragma unroll
            for (int i = 0; i < 16; ++i)
                s += vrow[lane + 64 * i] * wv[jj][lane + 64 * i];
            #pragma unroll
            for (int off = 32; off; off >>= 1) s += __shfl_xor(s, off);
            if (lane == 0) cv[((size_t)b * KA + k) * KA + jg * 7 + jj] = s;
        }
    }
}

// ---------------------------------------------------------------------------
// Vt[b][h][k(0..63)] = bf16(V[b][k][h]), k>=49 -> 0.  grid (64,16), block 256
// ---------------------------------------------------------------------------
__global__ void vt_kernel(const float* __restrict__ V, ushortt* __restrict__ Vt) {
    __shared__ float tile[KA][65];
    const int b = blockIdx.x, hg = blockIdx.y;
    const int tid = threadIdx.x;
    for (int idx = tid; idx < KA * 64; idx += 256) {
        int k = idx >> 6, c = idx & 63;
        tile[k][c] = V[(size_t)(b * KA + k) * HD + hg * 64 + c];
    }
    __syncthreads();
    const int c = tid & 63, kq = tid >> 6;
    ushortt tmp[16];
    #pragma unroll
    for (int u = 0; u < 16; ++u) {
        int k = kq * 16 + u;
        float f = (k < KA) ? tile[k][c] : 0.f;
        tmp[u] = (ushortt)f2bf1(f);
    }
    ushortt* dst = Vt + ((size_t)b * HD + hg * 64 + c) * 64 + kq * 16;
    ((uint4*)dst)[0] = *((const uint4*)tmp);
    ((uint4*)dst)[1] = *((const uint4*)(tmp + 8));
}

// ---------------------------------------------------------------------------
// gate_gemm2: s_t = sigmoid(xb @ Wxb^T) * tanh(cells), bf16 out.
// m97-style: 128x128 tile, BK=64, global_load_lds width-16.  grid (8, 256)
// ---------------------------------------------------------------------------
__launch_bounds__(256)
__global__ void gate_gemm2(const ushortt* __restrict__ xb, const ushortt* __restrict__ Wxb,
                           const float* __restrict__ cells, ushortt* __restrict__ s_t) {
    __shared__ ushortt As[128 * 64];
    __shared__ ushortt Bs[128 * 64];
    const int tid = threadIdx.x;
    const int w = tid >> 6, lane = tid & 63, quad = lane >> 4, l15 = lane & 15;
    const int n0 = blockIdx.x * 128, m0 = blockIdx.y * 128;
    const int wm = (w >> 1) * 64, wn = (w & 1) * 64;
    const int lrow = lane >> 3, lcol = lane & 7;
    f32x4 acc[4][4] = {};
    for (int kt = 0; kt < HD; kt += 64) {
        __syncthreads();
        #pragma unroll
        for (int it = 0; it < 4; ++it) {
            int c = w * 4 + it;
            int row = c * 8 + lrow;
            async_copy16(xb  + (size_t)(m0 + row) * HD + kt + lcol * 8, (char*)As + c * 1024);
            async_copy16(Wxb + (size_t)(n0 + row) * HD + kt + lcol * 8, (char*)Bs + c * 1024);
        }
        __syncthreads();
        #pragma unroll
        for (int kc = 0; kc < 2; ++kc) {
            bf16x8 af[4], bfr[4];
            #pragma unroll
            for (int i = 0; i < 4; ++i)
                af[i] = *((const bf16x8*)&As[(wm + i * 16 + l15) * 64 + kc * 32 + quad * 8]);
            #pragma unroll
            for (int j = 0; j < 4; ++j)
                bfr[j] = *((const bf16x8*)&Bs[(wn + j * 16 + l15) * 64 + kc * 32 + quad * 8]);
            #pragma unroll
            for (int i = 0; i < 4; ++i)
                #pragma unroll
                for (int j = 0; j < 4; ++j)
                    acc[i][j] = __builtin_amdgcn_mfma_f32_16x16x32_bf16(af[i], bfr[j], acc[i][j], 0, 0, 0);
        }
    }
    #pragma unroll
    for (int i = 0; i < 4; ++i) {
        #pragma unroll
        for (int reg = 0; reg < 4; ++reg) {
            int rowg = m0 + wm + i * 16 + quad * 4 + reg;
            const float* crow = cells + (size_t)rowg * HD;
            ushortt* srow = s_t + (size_t)rowg * HD;
            #pragma unroll
            for (int j = 0; j < 4; ++j) {
                int colg = n0 + wn + j * 16 + l15;
                float z = acc[i][j][reg];
                float sv = fast_sigmoid(z) * fast_tanh(crow[colg]);
                srow[colg] = (ushortt)f2bf1(sv);
            }
        }
    }
}

// ---------------------------------------------------------------------------
// small_gemm2: out[m][0..63] = A[m,:] @ B64[j,:]^T (A bf16, B64 bf16 padded).
// M-tile 128, N=64, BK=64, global_load_lds.  grid (256), block 256
// ---------------------------------------------------------------------------
__launch_bounds__(256)
__global__ void small_gemm2(const ushortt* __restrict__ A, const ushortt* __restrict__ B64,
                            float* __restrict__ outp) {
    __shared__ ushortt As[128 * 64];
    __shared__ ushortt Bs[64 * 64];
    const int tid = threadIdx.x;
    const int w = tid >> 6, lane = tid & 63, quad = lane >> 4, l15 = lane & 15;
    const int m0 = blockIdx.x * 128, wm = w * 32;
    const int lrow = lane >> 3, lcol = lane & 7;
    f32x4 acc[2][4] = {};
    for (int kt = 0; kt < HD; kt += 64) {
        __syncthreads();
        #pragma unroll
        for (int it = 0; it < 4; ++it) {
            int c = w * 4 + it;
            int row = c * 8 + lrow;
            async_copy16(A + (size_t)(m0 + row) * HD + kt + lcol * 8, (char*)As + c * 1024);
        }
        #pragma unroll
        for (int it = 0; it < 2; ++it) {
            int c = w * 2 + it;
            int row = c * 8 + lrow;           // 0..63
            async_copy16(B64 + (size_t)row * HD + kt + lcol * 8, (char*)Bs + c * 1024);
        }
        __syncthreads();
        #pragma unroll
        for (int kc = 0; kc < 2; ++kc) {
            bf16x8 af[2], bfr[4];
            #pragma unroll
            for (int i = 0; i < 2; ++i)
                af[i] = *((const bf16x8*)&As[(wm + i * 16 + l15) * 64 + kc * 32 + quad * 8]);
            #pragma unroll
            for (int j = 0; j < 4; ++j)
                bfr[j] = *((const bf16x8*)&Bs[(j * 16 + l15) * 64 + kc * 32 + quad * 8]);
            #pragma unroll
            for (int i = 0; i < 2; ++i)
                #pragma unroll
                for (int j = 0; j < 4; ++j)
                    acc[i][j] = __builtin_amdgcn_mfma_f32_16x16x32_bf16(af[i], bfr[j], acc[i][j], 0, 0, 0);
        }
    }
    #pragma unroll
    for (int i = 0; i < 2; ++i)
        #pragma unroll
        for (int reg = 0; reg < 4; ++reg) {
            int rowg = m0 + wm + i * 16 + quad * 4 + reg;
            #pragma unroll
            for (int j = 0; j < 4; ++j)
                outp[(size_t)rowg * 64 + j * 16 + l15] = acc[i][j][reg];
        }
}

// ---------------------------------------------------------------------------
// attention scores. grid (64, 8), block 256. lane = k.
// ---------------------------------------------------------------------------
__global__ void attn_kernel(const float* __restrict__ g, const float* __restrict__ ss,
                            const float* __restrict__ cv, const float* __restrict__ Wh,
                            ushortt* __restrict__ alpha, float* __restrict__ beta) {
    __shared__ float cvs[KA * KA];
    const int b = blockIdx.x, t0 = blockIdx.y * 64;
    const int tid = threadIdx.x, w = tid >> 6, lane = tid & 63;
    for (int idx = tid; idx < KA * KA; idx += 256)
        cvs[idx] = cv[(size_t)b * KA * KA + idx];
    const float wh_l = (lane < KA) ? Wh[lane] : 0.f;
    __syncthreads();
    for (int ti = 0; ti < 16; ++ti) {
        const int t = t0 + ti * 4 + w;
        const size_t row = (size_t)b * TT + t;
        const float gj  = g[row * 64 + lane];
        const float ssj = ss[row * 64 + lane] + gj;
        float ve = fast_tanh(ssj) * wh_l;
        #pragma unroll
        for (int off = 32; off; off >>= 1) ve += __shfl_xor(ve, off);
        float zk = 0.f;
        const float* cr = cvs + lane * KA;
        for (int j = 0; j < KA; ++j) {
            float gb = __shfl(gj, j);
            float wb = __shfl(wh_l, j);
            zk += fast_tanh(cr[j] + gb) * wb;
        }
        float zval = (lane < KA) ? zk : -1e30f;
        float M = zval;
        #pragma unroll
        for (int off = 32; off; off >>= 1) M = fmaxf(M, __shfl_xor(M, off));
        M = fmaxf(M, ve);
        float ek = (lane < KA) ? __expf(zk - M) : 0.f;
        float S = ek;
        #pragma unroll
        for (int off = 32; off; off >>= 1) S += __shfl_xor(S, off);
        float eext = __expf(ve - M);
        float bet  = eext * fast_rcp(S + eext);
        float al   = ek * fast_rcp(S);
        alpha[row * 64 + lane] = (ushortt)f2bf1(al);
        if (lane == 0) beta[row] = bet;
    }
}

// ---------------------------------------------------------------------------
// ct_final2: c_t = alpha @ Vt^T (K=64), out = beta*s_t + (1-beta)*c_t + hiddens
// M-tile 128, N-tile 64, LDS-bounce vector epilogue.  grid (16, 256)
// ---------------------------------------------------------------------------
__launch_bounds__(256)
__global__ void ct_final2(const ushortt* __restrict__ alpha, const ushortt* __restrict__ Vt,
                          const ushortt* __restrict__ s_t, const float* __restrict__ hiddens,
                          const float* __restrict__ beta, float* __restrict__ outp) {
    __shared__ __align__(16) char smem[128 * 68 * 4];   // 34816 B, aliased
    ushortt* As = (ushortt*)smem;                       // 128x64 bf16 = 16 KB
    ushortt* Bs = (ushortt*)(smem + 16384);             // 64x64 bf16 = 8 KB
    float*   cts = (float*)smem;                        // [128][68] fp32
    const int tid = threadIdx.x;
    const int w = tid >> 6, lane = tid & 63, quad = lane >> 4, l15 = lane & 15;
    const int n0 = blockIdx.x * 64, m0 = blockIdx.y * 128;
    const int b = m0 >> 9;                              // 512 rows per batch
    const int lrow = lane >> 3, lcol = lane & 7;
    const int wm = w * 32;
    #pragma unroll
    for (int it = 0; it < 4; ++it) {
        int c = w * 4 + it;
        async_copy16(alpha + (size_t)(m0 + c * 8 + lrow) * 64 + lcol * 8, (char*)As + c * 1024);
    }
    #pragma unroll
    for (int it = 0; it < 2; ++it) {
        int c = w * 2 + it;
        async_copy16(Vt + ((size_t)b * HD + n0 + c * 8 + lrow) * 64 + lcol * 8, (char*)Bs + c * 1024);
    }
    __syncthreads();
    f32x4 acc[2][4] = {};
    #pragma unroll
    for (int kc = 0; kc < 2; ++kc) {
        bf16x8 af[2], bfr[4];
        #pragma unroll
        for (int i = 0; i < 2; ++i)
            af[i] = *((const bf16x8*)&As[(wm + i * 16 + l15) * 64 + kc * 32 + quad * 8]);
        #pragma unroll
        for (int j = 0; j < 4; ++j)
            bfr[j] = *((const bf16x8*)&Bs[(j * 16 + l15) * 64 + kc * 32 + quad * 8]);
        #pragma unroll
        for (int i = 0; i < 2; ++i)
            #pragma unroll
            for (int j = 0; j < 4; ++j)
                acc[i][j] = __builtin_amdgcn_mfma_f32_16x16x32_bf16(af[i], bfr[j], acc[i][j], 0, 0, 0);
    }
    __syncthreads();
    #pragma unroll
    for (int i = 0; i < 2; ++i)
        #pragma unroll
        for (int reg = 0; reg < 4; ++reg)
            #pragma unroll
            for (int j = 0; j < 4; ++j)
                cts[(wm + i * 16 + quad * 4 + reg) * 68 + j * 16 + l15] = acc[i][j][reg];
    __syncthreads();
    const int c8 = tid & 7, r0 = tid >> 3;
    #pragma unroll
    for (int r = 0; r < 4; ++r) {
        int row = r0 + r * 32;
        int rowg = m0 + row;
        float bet = beta[rowg], omb = 1.f - bet;
        const ushortt* sp = s_t + (size_t)rowg * HD + n0 + c8 * 8;
        const float*   hp = hiddens + (size_t)rowg * HD + n0 + c8 * 8;
        float*         op = outp + (size_t)rowg * HD + n0 + c8 * 8;
        union { uint4 u4; ushortt us[8]; } sv;
        sv.u4 = *((const uint4*)sp);
        float4 h0 = ((const float4*)hp)[0], h1 = ((const float4*)hp)[1];
        const float* cp = cts + row * 68 + c8 * 8;
        float o[8];
        float hh[8] = {h0.x, h0.y, h0.z, h0.w, h1.x, h1.y, h1.z, h1.w};
        #pragma unroll
        for (int u = 0; u < 8; ++u)
            o[u] = bet * bf2f(sv.us[u]) + omb * cp[u] + hh[u];
        ((float4*)op)[0] = make_float4(o[0], o[1], o[2], o[3]);
        ((float4*)op)[1] = make_float4(o[4], o[5], o[6], o[7]);
    }
}

// ---------------------------------------------------------------------------
extern "C" void kernel_launch(void* const* d_in, const int* in_sizes, int n_in,
                              void* d_out, int out_size, void* d_ws, size_t ws_size,
                              hipStream_t stream) {
    (void)in_sizes; (void)n_in; (void)out_size; (void)ws_size;
    const float* x       = (const float*)d_in[0];
    const float* hiddens = (const float*)d_in[1];
    const float* cells   = (const float*)d_in[2];
    const float* V       = (const float*)d_in[3];
    const float* Wx      = (const float*)d_in[4];
    // d_in[5] = Whh — multiplied by h_prev==0; unused.
    const float* Wv      = (const float*)d_in[6];
    const float* Wg      = (const float*)d_in[7];
    const float* Ws      = (const float*)d_in[8];
    const float* Wh      = (const float*)d_in[9];
    float* out = (float*)d_out;

    // xb and hb live in d_out (2 x 67 MB = exactly out_size); both dead before ct_final2.
    ushortt* xb = (ushortt*)d_out;
    ushortt* hb = (ushortt*)d_out + (size_t)MR * HD;

    char* ws = (char*)d_ws;
    ushortt* s_t   = (ushortt*)ws;  ws += (size_t)MR * HD * 2;        // 67 MB
    ushortt* alpha = (ushortt*)ws;  ws += (size_t)MR * 64 * 2;        // 4 MB
    ushortt* Vt    = (ushortt*)ws;  ws += (size_t)BB * HD * 64 * 2;   // 8 MB
    float* gbuf = (float*)ws;       ws += (size_t)MR * 64 * 4;        // 8 MB
    float* ssb  = (float*)ws;       ws += (size_t)MR * 64 * 4;        // 8 MB
    float* cvb  = (float*)ws;       ws += (size_t)BB * KA * KA * 4;
    float* beta = (float*)ws;       ws += (size_t)MR * 4;
    ushortt* Wxb   = (ushortt*)ws;  ws += (size_t)HD * HD * 2;        // 2 MB
    ushortt* Wgb64 = (ushortt*)ws;  ws += (size_t)64 * HD * 2;
    ushortt* Wsb64 = (ushortt*)ws;  ws += (size_t)64 * HD * 2;

    f32_to_bf16<<<dim3(MR * HD / 8 / 256), dim3(256), 0, stream>>>(x, xb);
    f32_to_bf16<<<dim3(MR * HD / 8 / 256), dim3(256), 0, stream>>>(hiddens, hb);
    f32_to_bf16<<<dim3(HD * HD / 8 / 256), dim3(256), 0, stream>>>(Wx, Wxb);
    cvt_w49<<<dim3(32), dim3(256), 0, stream>>>(Wg, Wgb64);
    cvt_w49<<<dim3(32), dim3(256), 0, stream>>>(Ws, Wsb64);
    cv_kernel<<<dim3(BB, 7),  dim3(256), 0, stream>>>(V, Wv, cvb);
    vt_kernel<<<dim3(BB, 16), dim3(256), 0, stream>>>(V, Vt);
    small_gemm2<<<dim3(MR / 128), dim3(256), 0, stream>>>(hb, Wgb64, gbuf);
    gate_gemm2<<<dim3(8, MR / 128), dim3(256), 0, stream>>>(xb, Wxb, cells, s_t);
    small_gemm2<<<dim3(MR / 128), dim3(256), 0, stream>>>(s_t, Wsb64, ssb);
    attn_kernel<<<dim3(BB, 8), dim3(256), 0, stream>>>(gbuf, ssb, cvb, Wh, alpha, beta);
    ct_final2<<<dim3(16, MR / 128), dim3(256), 0, stream>>>(alpha, Vt, s_t, hiddens, beta, out);
}